// Round 1
// baseline (218.174 us; speedup 1.0000x reference)
//
#include <hip/hip_runtime.h>
#include <cstdint>
#include <cstddef>

#define BS 32
#define NA 8400
#define NM 64
#define NPRO 31
#define NALP 24
#define NADS 37
#define TOPK 13
#define FEPS 1e-9f
#define WORDS 264   // ceil(8400/32)=263, padded to 264

// output offsets (in floats), concatenated in reference return order
#define OFF0 0L          // target_pro      (32,8400)
#define OFF1 268800L     // target_alp      (32,8400)
#define OFF2 537600L     // target_ad0_4    (5,32,8400)
#define OFF3 1881600L    // target_bboxes   (32,8400,4)
#define OFF4 2956800L    // target_corners  (32,8400,8)
#define OFF5 5107200L    // pro_scores      (32,8400,31)
#define OFF6 13440000L   // alp_scores      (32,8400,24)
#define OFF7 19891200L   // ads_scores      (5,32,8400,37)
#define OFF8 69619200L   // fg_mask         (32,8400)

// ---------------- Kernel A: per-(b,m) metrics + top-13 + posmask ----------------
__global__ __launch_bounds__(256) void kA(
    const float* __restrict__ pro, const float* __restrict__ pd_bb,
    const float* __restrict__ anc, const int* __restrict__ gt_pro,
    const float* __restrict__ gt_bb, const float* __restrict__ mask_gt,
    unsigned* __restrict__ posmask, unsigned* __restrict__ posA,
    unsigned* __restrict__ posO)
{
  __shared__ float s_met[NA];
  __shared__ unsigned s_in[WORDS];
  __shared__ unsigned s_top[WORDS];
  __shared__ float s_rv[256];
  __shared__ int s_ri[256];

  const int bm = blockIdx.x;
  const int b = bm >> 6;
  const int m = bm & 63;
  const int tid = threadIdx.x;

  if (tid == 0) { posA[bm] = 0u; posO[bm] = 0u; }

  unsigned* pmrow = posmask + (size_t)b * WORDS * NM + m;  // index w*NM

  if (!(mask_gt[bm] > 0.f)) {   // invalid gt -> tidx forced to 0 -> counts>1 -> all zero
    for (int w = tid; w < WORDS; w += 256) pmrow[(size_t)w * NM] = 0u;
    return;
  }

  const float4 g = *(const float4*)(gt_bb + (size_t)bm * 4);
  const int label = gt_pro[bm];
  const float ga = fmaxf(g.z - g.x, 0.f) * fmaxf(g.w - g.y, 0.f);

  for (int w = tid; w < WORDS; w += 256) { s_in[w] = 0u; s_top[w] = 0u; }
  __syncthreads();

  const float* pb = pd_bb + (size_t)b * NA * 4;
  const float* ps = pro + (size_t)b * NA * NPRO + label;

  for (int a = tid; a < NA; a += 256) {
    float2 ap = *(const float2*)(anc + 2 * a);
    float din = fminf(fminf(ap.x - g.x, ap.y - g.y), fminf(g.z - ap.x, g.w - ap.y));
    float4 p = *(const float4*)(pb + (size_t)a * 4);
    float iw = fmaxf(fminf(g.z, p.z) - fmaxf(g.x, p.x), 0.f);
    float ih = fmaxf(fminf(g.w, p.w) - fmaxf(g.y, p.y), 0.f);
    float inter = iw * ih;
    float pa = fmaxf(p.z - p.x, 0.f) * fmaxf(p.w - p.y, 0.f);
    float iou = inter / (ga + pa - inter + FEPS);
    float met = 0.f;
    if (din > FEPS) {
      met = ps[(size_t)a * NPRO] * powf(iou, 6.0f);
      atomicOr(&s_in[a >> 5], 1u << (a & 31));
    }
    s_met[a] = met;
  }
  __syncthreads();

  // top-13: value desc, index asc (matches lax.top_k tie-breaking)
  for (int k = 0; k < TOPK; k++) {
    float bv = -2.f; int bi = NA;
    for (int a = tid; a < NA; a += 256) {
      float v = s_met[a];
      if (v > bv) { bv = v; bi = a; }   // ascending a: keeps lowest index on tie
    }
    s_rv[tid] = bv; s_ri[tid] = bi;
    __syncthreads();
    for (int s = 128; s > 0; s >>= 1) {
      if (tid < s) {
        float v = s_rv[tid + s]; int i = s_ri[tid + s];
        if (v > s_rv[tid] || (v == s_rv[tid] && i < s_ri[tid])) { s_rv[tid] = v; s_ri[tid] = i; }
      }
      __syncthreads();
    }
    if (tid == 0) {
      int w = s_ri[0];
      s_top[w >> 5] |= (1u << (w & 31));
      s_met[w] = -1.f;   // remove; all real metrics >= 0
    }
    __syncthreads();
  }

  for (int w = tid; w < WORDS; w += 256)
    pmrow[(size_t)w * NM] = s_top[w] & s_in[w];   // is_in_topk * mask_in (mask_gt already handled)
}

// ---------------- Kernel B: per-anchor resolve + pos_align/pos_ov atomics ----------------
__global__ __launch_bounds__(256) void kB(
    const float* __restrict__ pro, const float* __restrict__ pd_bb,
    const int* __restrict__ gt_pro, const float* __restrict__ gt_bb,
    const unsigned* __restrict__ posmask,
    unsigned* __restrict__ posA, unsigned* __restrict__ posO,
    int* __restrict__ tgi, float* __restrict__ fgo, float* __restrict__ avo)
{
  __shared__ float4 s_g[NM];
  __shared__ float s_ga[NM];
  __shared__ int s_lab[NM];
  __shared__ unsigned s_pm[8 * NM];   // [wlocal 0..7][m]

  const int b = blockIdx.y;
  const int a0 = blockIdx.x * 256;
  const int tid = threadIdx.x;

  if (tid < NM) {
    float4 gg = *(const float4*)(gt_bb + (size_t)(b * NM + tid) * 4);
    s_g[tid] = gg;
    s_ga[tid] = fmaxf(gg.z - gg.x, 0.f) * fmaxf(gg.w - gg.y, 0.f);
    s_lab[tid] = gt_pro[b * NM + tid];
  }
  const unsigned* pmb = posmask + (size_t)b * WORDS * NM;
  const int w0 = a0 >> 5;
  for (int i = tid; i < 8 * NM; i += 256)
    s_pm[i] = pmb[(size_t)(w0 + (i >> 6)) * NM + (i & 63)];
  __syncthreads();

  const int a = a0 + tid;
  if (a >= NA) return;

  float4 p = *(const float4*)(pd_bb + (size_t)(b * NA + a) * 4);
  float pa = fmaxf(p.z - p.x, 0.f) * fmaxf(p.w - p.y, 0.f);
  const unsigned sh = (unsigned)(a & 31);
  const int wloc = tid >> 5;

  int cnt = 0, first_m = 0, best_m = 0;
  float ov_first = 0.f, best_ov = -1.f;
  for (int m = 0; m < NM; m++) {
    float4 gg = s_g[m];
    float iw = fmaxf(fminf(gg.z, p.z) - fmaxf(gg.x, p.x), 0.f);
    float ih = fmaxf(fminf(gg.w, p.w) - fmaxf(gg.y, p.y), 0.f);
    float inter = iw * ih;
    float iou = inter / (s_ga[m] + pa - inter + FEPS);
    if (iou > best_ov) { best_ov = iou; best_m = m; }  // strict > : first max (jnp.argmax)
    unsigned bit = (s_pm[wloc * NM + m] >> sh) & 1u;
    if (bit) { cnt++; if (cnt == 1) { first_m = m; ov_first = iou; } }
  }

  int chosen; float ovv;
  if (cnt > 1)       { chosen = best_m;  ovv = best_ov; }
  else if (cnt == 1) { chosen = first_m; ovv = ov_first; }
  else               { chosen = 0;       ovv = 0.f; }
  float fg = (cnt > 0) ? 1.f : 0.f;

  float sc = pro[((size_t)b * NA + a) * NPRO + s_lab[chosen]];
  float av = sc * powf(ovv, 6.0f);

  const int ia = b * NA + a;
  tgi[ia] = chosen; fgo[ia] = fg; avo[ia] = av;
  if (cnt > 0) {
    atomicMax(&posA[b * NM + chosen], __float_as_uint(av));   // av,ovv >= 0: uint order == float order
    atomicMax(&posO[b * NM + chosen], __float_as_uint(ovv));
  }
}

// ---------------- Kernel C: gather targets + write all outputs ----------------
__global__ __launch_bounds__(256) void kC(
    const int* __restrict__ gt_pro, const int* __restrict__ gt_alp,
    const int* __restrict__ gt_ads, const float* __restrict__ gt_bb,
    const float* __restrict__ gt_cor,
    const unsigned* __restrict__ posA, const unsigned* __restrict__ posO,
    const int* __restrict__ tgi, const float* __restrict__ fgi,
    const float* __restrict__ avi, float* __restrict__ out)
{
  __shared__ int s_tp[256], s_ta[256];
  __shared__ int s_td[5][256];
  __shared__ float s_pv[256], s_fg[256];

  const int b = blockIdx.y;
  const int a0 = blockIdx.x * 256;
  const int tid = threadIdx.x;
  const int na = min(256, NA - a0);
  const int a = a0 + tid;

  if (a < NA) {
    const int ia = b * NA + a;
    const int g = tgi[ia];
    const float fg = fgi[ia];
    float no = 0.f;
    if (fg > 0.f) {
      no = avi[ia] * __uint_as_float(posO[b * NM + g]) /
           (__uint_as_float(posA[b * NM + g]) + FEPS);
    }
    const int gi = b * NM + g;
    const int tp = gt_pro[gi], ta = gt_alp[gi];
    s_tp[tid] = tp; s_ta[tid] = ta; s_pv[tid] = no; s_fg[tid] = fg;
    out[OFF0 + ia] = (float)tp;
    out[OFF1 + ia] = (float)ta;
#pragma unroll
    for (int k = 0; k < 5; k++) {
      int td = gt_ads[(size_t)gi * 5 + k];
      s_td[k][tid] = td;
      out[OFF2 + (size_t)k * (BS * NA) + ia] = (float)td;
    }
    float4 bb = *(const float4*)(gt_bb + (size_t)gi * 4);
    *(float4*)(out + OFF3 + (size_t)ia * 4) = bb;
    float4 c0 = *(const float4*)(gt_cor + (size_t)gi * 8);
    float4 c1 = *(const float4*)(gt_cor + (size_t)gi * 8 + 4);
    *(float4*)(out + OFF4 + (size_t)ia * 8) = c0;
    *(float4*)(out + OFF4 + (size_t)ia * 8 + 4) = c1;
    out[OFF8 + ia] = fg;
  }
  __syncthreads();

  // pro_scores one-hot * fg * norm
  {
    float* dst = out + OFF5 + ((size_t)b * NA + a0) * NPRO;
    const int n = na * NPRO;                 // divisible by 4 (na % 4 == 0)
    for (int e4 = tid * 4; e4 < n; e4 += 1024) {
      float vv[4];
#pragma unroll
      for (int j = 0; j < 4; j++) {
        int e = e4 + j; int al = e / NPRO; int c = e - al * NPRO;
        vv[j] = (c == s_tp[al]) ? s_pv[al] : 0.f;
      }
      *(float4*)(dst + e4) = make_float4(vv[0], vv[1], vv[2], vv[3]);
    }
  }
  // alp_scores one-hot * fg
  {
    float* dst = out + OFF6 + ((size_t)b * NA + a0) * NALP;
    const int n = na * NALP;
    for (int e4 = tid * 4; e4 < n; e4 += 1024) {
      float vv[4];
#pragma unroll
      for (int j = 0; j < 4; j++) {
        int e = e4 + j; int al = e / NALP; int c = e - al * NALP;
        vv[j] = (c == s_ta[al]) ? s_fg[al] : 0.f;
      }
      *(float4*)(dst + e4) = make_float4(vv[0], vv[1], vv[2], vv[3]);
    }
  }
  // ads_scores one-hot * fg, 5 heads
#pragma unroll
  for (int k = 0; k < 5; k++) {
    float* dst = out + OFF7 + (size_t)k * ((size_t)BS * NA * NADS) +
                 ((size_t)b * NA + a0) * NADS;
    const int n = na * NADS;
    for (int e4 = tid * 4; e4 < n; e4 += 1024) {
      float vv[4];
#pragma unroll
      for (int j = 0; j < 4; j++) {
        int e = e4 + j; int al = e / NADS; int c = e - al * NADS;
        vv[j] = (c == s_td[k][al]) ? s_fg[al] : 0.f;
      }
      *(float4*)(dst + e4) = make_float4(vv[0], vv[1], vv[2], vv[3]);
    }
  }
}

extern "C" void kernel_launch(void* const* d_in, const int* in_sizes, int n_in,
                              void* d_out, int out_size, void* d_ws, size_t ws_size,
                              hipStream_t stream) {
  const float* pd_pro  = (const float*)d_in[0];
  // d_in[1] pd_alp_scores, d_in[2] pd_ads_scores, d_in[4] pd_corners: unused by reference
  const float* pd_bb   = (const float*)d_in[3];
  const float* anc     = (const float*)d_in[5];
  const int*   gt_pro  = (const int*)d_in[6];
  const int*   gt_alp  = (const int*)d_in[7];
  const int*   gt_ads  = (const int*)d_in[8];
  const float* gt_bb   = (const float*)d_in[9];
  const float* gt_cor  = (const float*)d_in[10];
  const float* mask_gt = (const float*)d_in[11];
  float* out = (float*)d_out;

  char* ws = (char*)d_ws;
  unsigned* posmask = (unsigned*)(ws);                 // 32*264*64*4 = 2,162,688 B
  unsigned* posA    = (unsigned*)(ws + 2162688);       // 2048*4
  unsigned* posO    = (unsigned*)(ws + 2170880);       // 2048*4
  int*      tgi     = (int*)     (ws + 2179072);       // 268800*4
  float*    fgo     = (float*)   (ws + 3254272);       // 268800*4
  float*    avo     = (float*)   (ws + 4329472);       // 268800*4  (end: 5,404,672)

  kA<<<BS * NM, 256, 0, stream>>>(pd_pro, pd_bb, anc, gt_pro, gt_bb, mask_gt,
                                  posmask, posA, posO);
  dim3 gridBC((NA + 255) / 256, BS);
  kB<<<gridBC, 256, 0, stream>>>(pd_pro, pd_bb, gt_pro, gt_bb, posmask,
                                 posA, posO, tgi, fgo, avo);
  kC<<<gridBC, 256, 0, stream>>>(gt_pro, gt_alp, gt_ads, gt_bb, gt_cor,
                                 posA, posO, tgi, fgo, avo, out);
}

// Round 2
// 130.268 us; speedup vs baseline: 1.6748x; 1.6748x over previous
//
#include <hip/hip_runtime.h>
#include <cstdint>
#include <cstddef>

#define BS 32
#define NA 8400
#define NM 64
#define NPRO 31
#define NALP 24
#define NADS 37
#define TOPK 13
#define FEPS 1e-9f
#define WORDS 264   // ceil(8400/32)=263, padded
#define CAP 1024    // compact positive-metric list capacity (expected max ~350)

// output offsets (floats), concatenated in reference return order
#define OFF0 0L          // target_pro      (32,8400)
#define OFF1 268800L     // target_alp      (32,8400)
#define OFF2 537600L     // target_ad0_4    (5,32,8400)
#define OFF3 1881600L    // target_bboxes   (32,8400,4)
#define OFF4 2956800L    // target_corners  (32,8400,8)
#define OFF5 5107200L    // pro_scores      (32,8400,31)
#define OFF6 13440000L   // alp_scores      (32,8400,24)
#define OFF7 19891200L   // ads_scores      (5,32,8400,37)
#define OFF8 69619200L   // fg_mask         (32,8400)

__device__ __forceinline__ float iou1(float4 g, float ga, float4 p, float pa) {
  float iw = fmaxf(fminf(g.z, p.z) - fmaxf(g.x, p.x), 0.f);
  float ih = fmaxf(fminf(g.w, p.w) - fmaxf(g.y, p.y), 0.f);
  float inter = iw * ih;
  return inter / (ga + pa - inter + FEPS);
}

// ---------------- kZ: zero the scatter targets ----------------
__global__ __launch_bounds__(256) void kZ(unsigned long long* __restrict__ amask,
                                          unsigned* __restrict__ posA,
                                          unsigned* __restrict__ posO) {
  int i = blockIdx.x * 256 + threadIdx.x;
  if (i < BS * NA) amask[i] = 0ull;
  if (i < BS * NM) { posA[i] = 0u; posO[i] = 0u; }
}

// ---------------- kA: per-(b,m) sparse metrics + exact top-13 -> amask bits ----------------
__global__ __launch_bounds__(256) void kA(
    const float* __restrict__ pro, const float* __restrict__ pd_bb,
    const float* __restrict__ anc, const int* __restrict__ gt_pro,
    const float* __restrict__ gt_bb, const float* __restrict__ mask_gt,
    unsigned long long* __restrict__ amask)
{
  __shared__ unsigned s_in[WORDS];   // in-box bits
  __shared__ unsigned s_pos[WORDS];  // positive-metric bits
  __shared__ float s_cv[CAP];
  __shared__ int   s_ci[CAP];
  __shared__ int   s_cnt;

  const int bm = blockIdx.x;
  const int b = bm >> 6;
  const int m = bm & 63;
  const int tid = threadIdx.x;

  if (!(mask_gt[bm] > 0.f)) return;   // invalid gt -> no selections (counts>1 trick)

  for (int w = tid; w < WORDS; w += 256) { s_in[w] = 0u; s_pos[w] = 0u; }
  if (tid == 0) s_cnt = 0;
  __syncthreads();

  const float4 g = *(const float4*)(gt_bb + (size_t)bm * 4);
  const int label = gt_pro[bm];
  const float ga = fmaxf(g.z - g.x, 0.f) * fmaxf(g.w - g.y, 0.f);
  const float* pb = pd_bb + (size_t)b * NA * 4;
  const float* ps = pro + (size_t)b * NA * NPRO + label;

  for (int a = tid; a < NA; a += 256) {
    float2 ap = *(const float2*)(anc + 2 * a);
    float din = fminf(fminf(ap.x - g.x, ap.y - g.y), fminf(g.z - ap.x, g.w - ap.y));
    if (din > FEPS) {
      atomicOr(&s_in[a >> 5], 1u << (a & 31));
      float4 p = *(const float4*)(pb + (size_t)a * 4);
      float pa = fmaxf(p.z - p.x, 0.f) * fmaxf(p.w - p.y, 0.f);
      float iou = iou1(g, ga, p, pa);
      float i2 = iou * iou;
      float met = ps[(size_t)a * NPRO] * (i2 * i2 * i2);
      if (met > 0.f) {
        atomicOr(&s_pos[a >> 5], 1u << (a & 31));
        int pidx = atomicAdd(&s_cnt, 1);
        if (pidx < CAP) { s_cv[pidx] = met; s_ci[pidx] = a; }
      }
    }
  }
  __syncthreads();

  const int P = min(s_cnt, CAP);
  if (tid < 64) {
    // each lane owns entries tid, tid+64, ... in registers
    float lv[16]; int li[16];
#pragma unroll
    for (int e = 0; e < 16; e++) {
      int p = tid + e * 64;
      bool ok = p < P;
      lv[e] = ok ? s_cv[p] : -1.f;
      li[e] = ok ? s_ci[p] : NA;
    }
    const int nsel = min(P, TOPK);
    for (int k = 0; k < nsel; k++) {
      float bv = -1.f; int bi = NA;
#pragma unroll
      for (int e = 0; e < 16; e++)
        if (lv[e] > bv || (lv[e] == bv && li[e] < bi)) { bv = lv[e]; bi = li[e]; }
      for (int s = 1; s < 64; s <<= 1) {
        float ov = __shfl_xor(bv, s);
        int   oi = __shfl_xor(bi, s);
        if (ov > bv || (ov == bv && oi < bi)) { bv = ov; bi = oi; }
      }
      // winner (bv,bi) agreed by all lanes; clear owner copy
#pragma unroll
      for (int e = 0; e < 16; e++) if (li[e] == bi) lv[e] = -1.f;
      if (tid == 0) {
        // positives are in-box by construction; emit
        atomicOr(&amask[(size_t)b * NA + bi], 1ull << m);
      }
    }
    // fill remaining slots with lowest-index zero-metric anchors (tie at 0)
    if (tid == 0 && P < TOPK) {
      int need = TOPK - P;
      for (int a = 0; a < NA && need > 0; a++) {
        if (!((s_pos[a >> 5] >> (a & 31)) & 1u)) {
          need--;
          if ((s_in[a >> 5] >> (a & 31)) & 1u)
            atomicOr(&amask[(size_t)b * NA + a], 1ull << m);
        }
      }
    }
  }
}

// ---------------- kB: per-anchor resolve via popcount mask ----------------
__global__ __launch_bounds__(256) void kB(
    const float* __restrict__ pro, const float* __restrict__ pd_bb,
    const int* __restrict__ gt_pro, const float* __restrict__ gt_bb,
    const unsigned long long* __restrict__ amask,
    unsigned* __restrict__ posA, unsigned* __restrict__ posO,
    int* __restrict__ tgi, float* __restrict__ fgo, float* __restrict__ avo)
{
  __shared__ float4 s_g[NM];
  __shared__ float s_ga[NM];
  __shared__ int s_lab[NM];

  const int b = blockIdx.y;
  const int tid = threadIdx.x;
  const int a = blockIdx.x * 256 + tid;

  if (tid < NM) {
    float4 gg = *(const float4*)(gt_bb + (size_t)(b * NM + tid) * 4);
    s_g[tid] = gg;
    s_ga[tid] = fmaxf(gg.z - gg.x, 0.f) * fmaxf(gg.w - gg.y, 0.f);
    s_lab[tid] = gt_pro[b * NM + tid];
  }
  __syncthreads();
  if (a >= NA) return;

  const int ia = b * NA + a;
  unsigned long long msk = amask[ia];
  int cnt = __popcll(msk);
  int chosen = 0; float ovv = 0.f, av = 0.f, fg = 0.f;

  if (cnt > 0) {
    fg = 1.f;
    float4 p = *(const float4*)(pd_bb + (size_t)ia * 4);
    float pa = fmaxf(p.z - p.x, 0.f) * fmaxf(p.w - p.y, 0.f);
    if (cnt == 1) {
      chosen = __ffsll(msk) - 1;
      ovv = iou1(s_g[chosen], s_ga[chosen], p, pa);
    } else {
      float best = -1.f; int bmx = 0;
      for (int m = 0; m < NM; m++) {
        float v = iou1(s_g[m], s_ga[m], p, pa);
        if (v > best) { best = v; bmx = m; }   // strict >: first max (jnp.argmax)
      }
      chosen = bmx; ovv = best;
    }
    float sc = pro[(size_t)ia * NPRO + s_lab[chosen]];
    float o2 = ovv * ovv;
    av = sc * (o2 * o2 * o2);
    atomicMax(&posA[b * NM + chosen], __float_as_uint(av));  // values >= 0
    atomicMax(&posO[b * NM + chosen], __float_as_uint(ovv));
  }
  tgi[ia] = chosen; fgo[ia] = fg; avo[ia] = av;
}

// ---------------- kC: gather targets + write all outputs ----------------
__global__ __launch_bounds__(256) void kC(
    const int* __restrict__ gt_pro, const int* __restrict__ gt_alp,
    const int* __restrict__ gt_ads, const float* __restrict__ gt_bb,
    const float* __restrict__ gt_cor,
    const unsigned* __restrict__ posA, const unsigned* __restrict__ posO,
    const int* __restrict__ tgi, const float* __restrict__ fgi,
    const float* __restrict__ avi, float* __restrict__ out)
{
  __shared__ int s_tp[256], s_ta[256];
  __shared__ int s_td[5][256];
  __shared__ float s_pv[256], s_fg[256];

  const int b = blockIdx.y;
  const int a0 = blockIdx.x * 256;
  const int tid = threadIdx.x;
  const int na = min(256, NA - a0);
  const int a = a0 + tid;

  if (a < NA) {
    const int ia = b * NA + a;
    const int g = tgi[ia];
    const float fg = fgi[ia];
    float no = 0.f;
    if (fg > 0.f) {
      no = avi[ia] * __uint_as_float(posO[b * NM + g]) /
           (__uint_as_float(posA[b * NM + g]) + FEPS);
    }
    const int gi = b * NM + g;
    const int tp = gt_pro[gi], ta = gt_alp[gi];
    s_tp[tid] = tp; s_ta[tid] = ta; s_pv[tid] = no; s_fg[tid] = fg;
    out[OFF0 + ia] = (float)tp;
    out[OFF1 + ia] = (float)ta;
#pragma unroll
    for (int k = 0; k < 5; k++) {
      int td = gt_ads[(size_t)gi * 5 + k];
      s_td[k][tid] = td;
      out[OFF2 + (size_t)k * (BS * NA) + ia] = (float)td;
    }
    float4 bb = *(const float4*)(gt_bb + (size_t)gi * 4);
    *(float4*)(out + OFF3 + (size_t)ia * 4) = bb;
    float4 c0 = *(const float4*)(gt_cor + (size_t)gi * 8);
    float4 c1 = *(const float4*)(gt_cor + (size_t)gi * 8 + 4);
    *(float4*)(out + OFF4 + (size_t)ia * 8) = c0;
    *(float4*)(out + OFF4 + (size_t)ia * 8 + 4) = c1;
    out[OFF8 + ia] = fg;
  }
  __syncthreads();

  // pro_scores one-hot * norm
  {
    float* dst = out + OFF5 + ((size_t)b * NA + a0) * NPRO;
    const int n = na * NPRO;
    for (int e4 = tid * 4; e4 < n; e4 += 1024) {
      float vv[4];
#pragma unroll
      for (int j = 0; j < 4; j++) {
        int e = e4 + j; int al = e / NPRO; int c = e - al * NPRO;
        vv[j] = (c == s_tp[al]) ? s_pv[al] : 0.f;
      }
      *(float4*)(dst + e4) = make_float4(vv[0], vv[1], vv[2], vv[3]);
    }
  }
  // alp_scores one-hot * fg
  {
    float* dst = out + OFF6 + ((size_t)b * NA + a0) * NALP;
    const int n = na * NALP;
    for (int e4 = tid * 4; e4 < n; e4 += 1024) {
      float vv[4];
#pragma unroll
      for (int j = 0; j < 4; j++) {
        int e = e4 + j; int al = e / NALP; int c = e - al * NALP;
        vv[j] = (c == s_ta[al]) ? s_fg[al] : 0.f;
      }
      *(float4*)(dst + e4) = make_float4(vv[0], vv[1], vv[2], vv[3]);
    }
  }
  // ads_scores one-hot * fg, 5 heads
#pragma unroll
  for (int k = 0; k < 5; k++) {
    float* dst = out + OFF7 + (size_t)k * ((size_t)BS * NA * NADS) +
                 ((size_t)b * NA + a0) * NADS;
    const int n = na * NADS;
    for (int e4 = tid * 4; e4 < n; e4 += 1024) {
      float vv[4];
#pragma unroll
      for (int j = 0; j < 4; j++) {
        int e = e4 + j; int al = e / NADS; int c = e - al * NADS;
        vv[j] = (c == s_td[k][al]) ? s_fg[al] : 0.f;
      }
      *(float4*)(dst + e4) = make_float4(vv[0], vv[1], vv[2], vv[3]);
    }
  }
}

extern "C" void kernel_launch(void* const* d_in, const int* in_sizes, int n_in,
                              void* d_out, int out_size, void* d_ws, size_t ws_size,
                              hipStream_t stream) {
  const float* pd_pro  = (const float*)d_in[0];
  const float* pd_bb   = (const float*)d_in[3];
  const float* anc     = (const float*)d_in[5];
  const int*   gt_pro  = (const int*)d_in[6];
  const int*   gt_alp  = (const int*)d_in[7];
  const int*   gt_ads  = (const int*)d_in[8];
  const float* gt_bb   = (const float*)d_in[9];
  const float* gt_cor  = (const float*)d_in[10];
  const float* mask_gt = (const float*)d_in[11];
  float* out = (float*)d_out;

  char* ws = (char*)d_ws;
  unsigned long long* amask = (unsigned long long*)(ws);     // 32*8400*8 = 2,150,400
  unsigned* posA = (unsigned*)(ws + 2150400);                // 2048*4
  unsigned* posO = (unsigned*)(ws + 2158592);                // 2048*4
  int*      tgi  = (int*)     (ws + 2166784);                // 268800*4
  float*    fgo  = (float*)   (ws + 3241984);                // 268800*4
  float*    avo  = (float*)   (ws + 4317184);                // 268800*4 (end 5,392,384)

  kZ<<<(BS * NA + 255) / 256, 256, 0, stream>>>(amask, posA, posO);
  kA<<<BS * NM, 256, 0, stream>>>(pd_pro, pd_bb, anc, gt_pro, gt_bb, mask_gt, amask);
  dim3 gridBC((NA + 255) / 256, BS);
  kB<<<gridBC, 256, 0, stream>>>(pd_pro, pd_bb, gt_pro, gt_bb, amask,
                                 posA, posO, tgi, fgo, avo);
  kC<<<gridBC, 256, 0, stream>>>(gt_pro, gt_alp, gt_ads, gt_bb, gt_cor,
                                 posA, posO, tgi, fgo, avo, out);
}